// Round 4
// baseline (484.734 us; speedup 1.0000x reference)
//
#include <hip/hip_runtime.h>
#include <hip/hip_bf16.h>
#include <stdint.h>

#define LOG2E 1.44269504088896340736f
#define LN2   0.69314718055994530942f

typedef __attribute__((ext_vector_type(8))) __bf16 bf16x8;
typedef __attribute__((ext_vector_type(4))) float  f32x4;

static constexpr int B = 128, S = 512, T = 256;
static constexpr int LDP = T + 8;   // padded LDS row (bf16 elems)
static constexpr int H   = 260;     // forward covers s=1..H, backward s=S-1..H+1
static constexpr int NSF = H;           // 260 forward steps
static constexpr int NSB = S - 1 - H;   // 251 backward steps

static __device__ __forceinline__ uint pack_bf16x2(float a, float b) {
    __hip_bfloat162 h = __float22bfloat162_rn(make_float2(a, b));
    union { __hip_bfloat162 h; uint u; } cv; cv.h = h;
    return cv.u;
}
static __device__ __forceinline__ float bf2f(ushort u) {
    return __uint_as_float(((uint)u) << 16);
}

// lgkm-only barrier: LDS writes must be visible, but leave global loads in
// flight (no vmcnt drain).  sched_barrier stops motion across it (rule #18).
static __device__ __forceinline__ void wg_barrier() {
    asm volatile("s_waitcnt lgkmcnt(0)" ::: "memory");
    __builtin_amdgcn_s_barrier();
    __builtin_amdgcn_sched_barrier(0);
}

// fmax over the 2x4 epilogue tile in a FIXED order so every path (either
// chain, tracked or rn-only) produces bitwise-equal maxima.
static __device__ __forceinline__ float vmax24(const float v[2][4]) {
    float m = 0.0f;
    #pragma unroll
    for (int t = 0; t < 2; ++t)
        #pragma unroll
        for (int r = 0; r < 4; ++r) m = fmaxf(m, v[t][r]);
    return m;
}

// ---- prep: Et[j][i] = bf16(exp(trans[i][j])), Em[i][j] = bf16(exp(trans[i][j]))
__global__ void prep_mats(const float* __restrict__ trans,
                          ushort* __restrict__ Et, ushort* __restrict__ Em) {
    int i = blockIdx.x;    // 256 (row of trans)
    int j = threadIdx.x;   // 256
    float e = exp2f(trans[i * T + j] * LOG2E);
    uint u = __float_as_uint(e);
    ushort h = (ushort)((u + 0x7FFFu + ((u >> 16) & 1u)) >> 16);  // RTNE
    Em[i * T + j] = h;     // exp(trans) row-major   (backward A-operand)
    Et[j * T + i] = h;     // exp(trans) transposed  (forward  A-operand)
}

// ---- prep: emx = bf16(exp(em)), elementwise over B*S*T
__global__ void prep_emx(const float* __restrict__ em, ushort* __restrict__ emx) {
    size_t i4 = ((size_t)blockIdx.x * blockDim.x + threadIdx.x) * 4;
    f32x4 e = *reinterpret_cast<const f32x4*>(&em[i4]);
    uint2 w;
    w.x = pack_bf16x2(exp2f(e[0] * LOG2E), exp2f(e[1] * LOG2E));
    w.y = pack_bf16x2(exp2f(e[2] * LOG2E), exp2f(e[3] * LOG2E));
    *reinterpret_cast<uint2*>(&emx[i4]) = w;
}

// ---- paired scan body: ONE WG runs BOTH scans (partition c=0, score c=1)
// of one direction for one batch-group.  The two chains are independent
// recurrences sharing em data, A fragments and the per-superstep barrier,
// so their dependency chains overlap inside one latency window: 2 steps
// retired per barrier round-trip.
// 8 waves (512 thr); wave w owns j in [32w, 32w+32).
template<bool PRE, int DIR>
static __device__ __forceinline__ void scan_pair_body(
    const float* __restrict__ em, const ushort* __restrict__ emx,
    const int* __restrict__ mask, const float* __restrict__ startt,
    const float* __restrict__ endt, const ushort* __restrict__ Amat,
    float* __restrict__ vecbuf, int* __restrict__ lsbuf, const int bg,
    ushort (&Al)[2][2][16][LDP], float (&mx2)[2][16][8])
{
    constexpr int NSTEP = DIR ? NSB : NSF;
    constexpr int PGRP  = (NSTEP + 7) / 8;

    const int tid  = threadIdx.x;
    const int w    = tid >> 6;          // wave 0..7
    const int lane = tid & 63;
    const int q    = lane >> 4;         // quad 0..3
    const int l    = lane & 15;         // local batch 0..15
    const int b    = bg * 16 + l;

    // step idx -> em row (epilogue) / mask row (the where())
    #define EROW(ix) (DIR ? (S - 2 - (ix)) : (1 + (ix)))
    #define MROW(ix) (DIR ? (S - 1 - (ix)) : (1 + (ix)))

    // ---- A fragments (step-invariant, shared by both chains): 64 VGPRs
    bf16x8 Afr[2][8];
    #pragma unroll
    for (int t = 0; t < 2; ++t) {
        int j = w * 32 + t * 16 + l;
        #pragma unroll
        for (int kt = 0; kt < 8; ++kt)
            Afr[t][kt] = *reinterpret_cast<const bf16x8*>(&Amat[j * T + kt * 32 + q * 8]);
    }

    const float*  emrow = em  + (size_t)b * S * T;
    const ushort* exrow = PRE ? emx + (size_t)b * S * T : nullptr;
    const int*    mrow  = mask + (size_t)b * S;

    int ls[2] = {0, 0};
    int buf = 0;
    float areg[2][2][4];   // DIR=1: raw beta (pre-em), scaled, per chain.

    // ---- init (identical for both chains; mask does not affect step 0)
    {
        const int    r0 = DIR ? (S - 1) : 0;
        const float* tv = DIR ? endt : startt;
        float v0[2][4], gg[2][4]; float mx = 0.0f;
        #pragma unroll
        for (int t = 0; t < 2; ++t) {
            int j0 = w * 32 + t * 16 + q * 4;
            f32x4 e4 = *reinterpret_cast<const f32x4*>(&emrow[(size_t)r0 * T + j0]);
            f32x4 s4 = *reinterpret_cast<const f32x4*>(&tv[j0]);
            #pragma unroll
            for (int r = 0; r < 4; ++r) {
                float full = exp2f((e4[r] + s4[r]) * LOG2E);
                v0[t][r] = full;
                gg[t][r] = DIR ? exp2f(s4[r] * LOG2E) : full;
                mx = fmaxf(mx, full);
            }
        }
        mx = fmaxf(mx, __shfl_xor(mx, 16));
        mx = fmaxf(mx, __shfl_xor(mx, 32));
        if (q == 0) { mx2[0][l][w] = mx; mx2[1][l][w] = mx; }
        __syncthreads();
        f32x4 ma = *reinterpret_cast<const f32x4*>(&mx2[0][l][0]);
        f32x4 mb = *reinterpret_cast<const f32x4*>(&mx2[0][l][4]);
        float gmx = fmaxf(fmaxf(fmaxf(ma[0], ma[1]), fmaxf(ma[2], ma[3])),
                          fmaxf(fmaxf(mb[0], mb[1]), fmaxf(mb[2], mb[3])));
        int e = (int)((__float_as_uint(gmx) >> 23) & 255u) - 127;
        float sc = __uint_as_float((uint)(127 - e) << 23);   // exact 2^-e
        ls[0] = e; ls[1] = e;
        #pragma unroll
        for (int t = 0; t < 2; ++t) {
            int j0 = w * 32 + t * 16 + q * 4;
            uint2 wv;
            wv.x = pack_bf16x2(v0[t][0] * sc, v0[t][1] * sc);
            wv.y = pack_bf16x2(v0[t][2] * sc, v0[t][3] * sc);
            *reinterpret_cast<uint2*>(&Al[0][0][l][j0]) = wv;
            *reinterpret_cast<uint2*>(&Al[1][0][l][j0]) = wv;
            if (DIR) {
                #pragma unroll
                for (int r = 0; r < 4; ++r) {
                    areg[0][t][r] = gg[t][r] * sc;
                    areg[1][t][r] = gg[t][r] * sc;
                }
            }
        }
        __syncthreads();
        if (q == 0) { mx2[0][l][w] = mx * sc; mx2[1][l][w] = mx * sc; }
        __syncthreads();
    }

    // ---- preload em/mask for group 0 (idx 0..7); em shared by both chains
    uint2 exv[8][2]; int mks[8];
    #pragma unroll
    for (int u = 0; u < 8; ++u) {
        int iu = u < NSTEP ? u : NSTEP - 1;
        #pragma unroll
        for (int t = 0; t < 2; ++t) {
            int j0 = w * 32 + t * 16 + q * 4;
            if (PRE) exv[u][t] = *reinterpret_cast<const uint2*>(&exrow[(size_t)EROW(iu) * T + j0]);
        }
        mks[u] = (u < NSTEP) ? mrow[MROW(iu)] : 1;
    }

    for (int p = 0; p < PGRP; ++p) {
        // ---- issue next group's loads now (stay in flight across barriers)
        uint2 exn[8][2]; int mkn[8];
        #pragma unroll
        for (int u = 0; u < 8; ++u) {
            int idx  = 8 * (p + 1) + u;
            int idxc = idx < NSTEP ? idx : NSTEP - 1;
            #pragma unroll
            for (int t = 0; t < 2; ++t) {
                int j0 = w * 32 + t * 16 + q * 4;
                if (PRE) exn[u][t] = *reinterpret_cast<const uint2*>(&exrow[(size_t)EROW(idxc) * T + j0]);
            }
            mkn[u] = (idx < NSTEP) ? mrow[MROW(idxc)] : 1;
        }

        float pend[2] = {1.0f, 1.0f}, vml1 = 0.0f;
        int pk[2] = {0, 0};

        #pragma unroll
        for (int u = 0; u < 8; ++u) {
            const int idx = 8 * p + u;
            if (idx < NSTEP) {
                if ((u & 3) == 0) {   // renorm-group start: per-chain kappa
                    #pragma unroll
                    for (int c = 0; c < 2; ++c) {
                        f32x4 ma = *reinterpret_cast<const f32x4*>(&mx2[c][l][0]);
                        f32x4 mb = *reinterpret_cast<const f32x4*>(&mx2[c][l][4]);
                        float gmx = fmaxf(fmaxf(fmaxf(ma[0], ma[1]), fmaxf(ma[2], ma[3])),
                                          fmaxf(fmaxf(mb[0], mb[1]), fmaxf(mb[2], mb[3])));
                        int kap = (int)((__float_as_uint(gmx) >> 23) & 255u) - 127;
                        pend[c] = __uint_as_float((uint)(127 - kap) << 23);
                        pk[c]   = kap;
                        if (c == 1) vml1 = gmx;
                    }
                }
                const int nb = buf ^ 1;

                // ---- both chains' MFMA blocks (independent dep chains)
                f32x4 acc[2][2];
                #pragma unroll
                for (int c = 0; c < 2; ++c) {
                    bf16x8 bfr[8];
                    #pragma unroll
                    for (int kt = 0; kt < 8; ++kt)
                        bfr[kt] = *reinterpret_cast<const bf16x8*>(&Al[c][buf][l][kt * 32 + q * 8]);
                    f32x4 ac[2][2] = {{f32x4{0,0,0,0}, f32x4{0,0,0,0}},
                                      {f32x4{0,0,0,0}, f32x4{0,0,0,0}}};
                    #pragma unroll
                    for (int kt = 0; kt < 8; ++kt) {
                        #pragma unroll
                        for (int t = 0; t < 2; ++t)
                            ac[t][kt & 1] = __builtin_amdgcn_mfma_f32_16x16x32_bf16(Afr[t][kt], bfr[kt], ac[t][kt & 1], 0, 0, 0);
                    }
                    acc[c][0] = ac[0][0] + ac[0][1];
                    acc[c][1] = ac[1][0] + ac[1][1];
                }

                // ---- shared em decode
                float e_[2][4];
                #pragma unroll
                for (int t = 0; t < 2; ++t) {
                    if (PRE) {
                        e_[t][0] = bf2f((ushort)(exv[u][t].x & 0xFFFF));
                        e_[t][1] = bf2f((ushort)(exv[u][t].x >> 16));
                        e_[t][2] = bf2f((ushort)(exv[u][t].y & 0xFFFF));
                        e_[t][3] = bf2f((ushort)(exv[u][t].y >> 16));
                    } else {
                        int j0 = w * 32 + t * 16 + q * 4;
                        f32x4 e4 = *reinterpret_cast<const f32x4*>(&emrow[(size_t)EROW(idx) * T + j0]);
                        #pragma unroll
                        for (int r = 0; r < 4; ++r) e_[t][r] = exp2f(e4[r] * LOG2E);
                    }
                }

                const int mk1 = mks[u];
                float v[2][2][4];

                // ---- chain 0 epilogue (partition: mk == 1 by construction)
                #pragma unroll
                for (int t = 0; t < 2; ++t) {
                    #pragma unroll
                    for (int r = 0; r < 4; ++r) {
                        if (DIR == 0) {
                            v[0][t][r] = acc[0][t][r] * e_[t][r] * pend[0];
                        } else {
                            float g = acc[0][t][r] * pend[0];
                            areg[0][t][r] = g;
                            v[0][t][r] = g * e_[t][r];
                        }
                    }
                }
                // ---- chain 1 epilogue (score: runtime mask)
                #pragma unroll
                for (int t = 0; t < 2; ++t) {
                    #pragma unroll
                    for (int r = 0; r < 4; ++r) {
                        if (DIR == 0) {
                            v[1][t][r] = acc[1][t][r] * e_[t][r] * pend[1];
                        } else {
                            float g  = acc[1][t][r] * pend[1];
                            float sv = mk1 ? g : areg[1][t][r];
                            areg[1][t][r] = sv;
                            v[1][t][r] = sv * e_[t][r];
                        }
                    }
                }

                // ---- LDS writes
                #pragma unroll
                for (int t = 0; t < 2; ++t) {       // chain 0: always store
                    int j0 = w * 32 + t * 16 + q * 4;
                    uint2 wv;
                    wv.x = pack_bf16x2(v[0][t][0], v[0][t][1]);
                    wv.y = pack_bf16x2(v[0][t][2], v[0][t][3]);
                    *reinterpret_cast<uint2*>(&Al[0][nb][l][j0]) = wv;
                }
                if (DIR == 0) {
                    if (mk1) {
                        #pragma unroll
                        for (int t = 0; t < 2; ++t) {
                            int j0 = w * 32 + t * 16 + q * 4;
                            uint2 wv;
                            wv.x = pack_bf16x2(v[1][t][0], v[1][t][1]);
                            wv.y = pack_bf16x2(v[1][t][2], v[1][t][3]);
                            *reinterpret_cast<uint2*>(&Al[1][nb][l][j0]) = wv;
                        }
                    } else {
                        #pragma unroll
                        for (int t = 0; t < 2; ++t) {
                            int j0 = w * 32 + t * 16 + q * 4;
                            *reinterpret_cast<uint2*>(&Al[1][nb][l][j0]) =
                                *reinterpret_cast<const uint2*>(&Al[1][buf][l][j0]);
                        }
                    }
                } else {
                    #pragma unroll
                    for (int t = 0; t < 2; ++t) {
                        int j0 = w * 32 + t * 16 + q * 4;
                        uint2 wv;
                        wv.x = pack_bf16x2(v[1][t][0], v[1][t][1]);
                        wv.y = pack_bf16x2(v[1][t][2], v[1][t][3]);
                        *reinterpret_cast<uint2*>(&Al[1][nb][l][j0]) = wv;
                    }
                }

                // ---- bookkeeping
                ls[0] += pk[0]; pend[0] = 1.0f; pk[0] = 0;
                ls[1] += mk1 ? pk[1] : 0;
                pend[1] = mk1 ? 1.0f : pend[1];
                pk[1]   = mk1 ? 0 : pk[1];
                if (DIR == 0) {   // score fwd: stored vec may persist -> track
                    float lmx = vmax24(v[1]);
                    vml1 = mk1 ? lmx : vml1;
                }

                const bool rn = ((u & 3) == 3) || (idx == NSTEP - 1);
                if (rn) {   // publish stored-vector max per chain
                    float f0 = vmax24(v[0]);
                    f0 = fmaxf(f0, __shfl_xor(f0, 16));
                    f0 = fmaxf(f0, __shfl_xor(f0, 32));
                    float f1 = (DIR == 0) ? vml1 : vmax24(v[1]);
                    f1 = fmaxf(f1, __shfl_xor(f1, 16));
                    f1 = fmaxf(f1, __shfl_xor(f1, 32));
                    if (q == 0) { mx2[0][l][w] = f0; mx2[1][l][w] = f1; }
                }

                wg_barrier();
                buf = nb;
            }
        }

        #pragma unroll
        for (int u = 0; u < 8; ++u) {
            #pragma unroll
            for (int t = 0; t < 2; ++t) exv[u][t] = exn[u][t];
            mks[u] = mkn[u];
        }
    }

    // ---- write mid vectors + exponents to workspace
    #pragma unroll
    for (int c = 0; c < 2; ++c) {
        const int cidx = c * 2 + DIR;
        if (DIR) {
            #pragma unroll
            for (int t = 0; t < 2; ++t) {
                int j0 = w * 32 + t * 16 + q * 4;
                f32x4 o = {areg[c][t][0], areg[c][t][1], areg[c][t][2], areg[c][t][3]};
                *reinterpret_cast<f32x4*>(&vecbuf[((size_t)cidx * B + b) * T + j0]) = o;
            }
        } else {
            #pragma unroll
            for (int t = 0; t < 2; ++t) {
                int j0 = w * 32 + t * 16 + q * 4;
                uint2 wv = *reinterpret_cast<const uint2*>(&Al[c][buf][l][j0]);
                f32x4 o = {bf2f((ushort)(wv.x & 0xFFFF)), bf2f((ushort)(wv.x >> 16)),
                           bf2f((ushort)(wv.y & 0xFFFF)), bf2f((ushort)(wv.y >> 16))};
                *reinterpret_cast<f32x4*>(&vecbuf[((size_t)cidx * B + b) * T + j0]) = o;
            }
        }
        if (w == 0 && q == 0) lsbuf[cidx * B + b] = ls[c];
    }

    #undef EROW
    #undef MROW
}

template<bool PRE>
__launch_bounds__(512, 2)
__global__ void crf_scan(const float* __restrict__ em,
                         const ushort* __restrict__ emx,
                         const int* __restrict__ mask,
                         const float* __restrict__ startt,
                         const float* __restrict__ endt,
                         const ushort* __restrict__ Et,     // fwd A
                         const ushort* __restrict__ Emat,   // bwd A
                         float* __restrict__ vecbuf,
                         int* __restrict__ lsbuf)
{
    __shared__ __align__(16) ushort Al[2][2][16][LDP];   // [chain][dbuf][b][j]
    __shared__ __align__(16) float mx2[2][16][8];        // [chain][b][wave]

    const int dir = blockIdx.x & 1;
    const int bg  = blockIdx.x >> 1;   // 0..7

    if (dir == 0)
        scan_pair_body<PRE, 0>(em, emx, mask, startt, endt, Et,   vecbuf, lsbuf, bg, Al, mx2);
    else
        scan_pair_body<PRE, 1>(em, emx, mask, startt, endt, Emat, vecbuf, lsbuf, bg, Al, mx2);
}

// ---- combine: res[scan][b] = ls_f + ls_b + log2(dot(alpha_H, G_{H+1}));
//      out[b] = (partition - score) * ln2
__global__ void combine2(const float* __restrict__ vecbuf, const int* __restrict__ lsbuf,
                         float* __restrict__ out) {
    __shared__ float r2[2][B];
    int tid = threadIdx.x;          // 256
    int sc_ = tid >> 7, b = tid & 127;
    const float* vf = vecbuf + ((size_t)(sc_ * 2 + 0) * B + b) * T;
    const float* vb = vecbuf + ((size_t)(sc_ * 2 + 1) * B + b) * T;
    float dot = 0.0f;
    for (int j = 0; j < T; j += 4) {
        f32x4 a = *reinterpret_cast<const f32x4*>(&vf[j]);
        f32x4 c = *reinterpret_cast<const f32x4*>(&vb[j]);
        dot += a[0] * c[0] + a[1] * c[1] + a[2] * c[2] + a[3] * c[3];
    }
    r2[sc_][b] = (float)(lsbuf[(sc_ * 2) * B + b] + lsbuf[(sc_ * 2 + 1) * B + b]) + log2f(dot);
    __syncthreads();
    if (tid < B) out[tid] = (r2[0][tid] - r2[1][tid]) * LN2;
}

extern "C" void kernel_launch(void* const* d_in, const int* in_sizes, int n_in,
                              void* d_out, int out_size, void* d_ws, size_t ws_size,
                              hipStream_t stream) {
    (void)in_sizes; (void)n_in; (void)out_size;
    const float* em = (const float*)d_in[0];
    const int*   mk = (const int*)d_in[1];
    const float* st = (const float*)d_in[2];
    const float* en = (const float*)d_in[3];
    const float* tr = (const float*)d_in[4];

    const size_t emx_bytes = (size_t)B * S * T * sizeof(ushort);   // 32 MiB
    const size_t mat_bytes = (size_t)T * T * sizeof(ushort);       // 128 KiB
    const size_t vec_bytes = (size_t)4 * B * T * sizeof(float);    // 512 KiB
    const size_t ls_bytes  = (size_t)4 * B * sizeof(int);          // 2 KiB

    const bool pre = ws_size >= emx_bytes + 2 * mat_bytes + vec_bytes + ls_bytes;

    char* wp = (char*)d_ws;
    ushort* emx = nullptr;
    if (pre) { emx = (ushort*)wp; wp += emx_bytes; }
    ushort* Et = (ushort*)wp; wp += mat_bytes;
    ushort* Em = (ushort*)wp; wp += mat_bytes;
    float*  vec = (float*)wp; wp += vec_bytes;
    int*    lsb = (int*)wp;

    prep_mats<<<T, T, 0, stream>>>(tr, Et, Em);
    if (pre) {
        prep_emx<<<(B * S * T) / (256 * 4), 256, 0, stream>>>(em, emx);
        crf_scan<true><<<16, 512, 0, stream>>>(em, emx, mk, st, en, Et, Em, vec, lsb);
    } else {
        crf_scan<false><<<16, 512, 0, stream>>>(em, emx, mk, st, en, Et, Em, vec, lsb);
    }
    combine2<<<1, 256, 0, stream>>>(vec, lsb, (float*)d_out);
}

// Round 5
// 417.066 us; speedup vs baseline: 1.1622x; 1.1622x over previous
//
#include <hip/hip_runtime.h>
#include <hip/hip_bf16.h>
#include <stdint.h>

#define LOG2E 1.44269504088896340736f
#define LN2   0.69314718055994530942f

typedef __attribute__((ext_vector_type(8))) __bf16 bf16x8;
typedef __attribute__((ext_vector_type(4))) float  f32x4;

static constexpr int B = 128, S = 512, T = 256;
static constexpr int LDP = T + 8;   // padded LDS row (bf16 elems)
static constexpr int H   = 258;     // forward covers s=1..H, backward s=S-1..H+1
static constexpr int NSF = H;           // 258 forward steps
static constexpr int NSB = S - 1 - H;   // 253 backward steps

static __device__ __forceinline__ uint pack_bf16x2(float a, float b) {
    __hip_bfloat162 h = __float22bfloat162_rn(make_float2(a, b));
    union { __hip_bfloat162 h; uint u; } cv; cv.h = h;
    return cv.u;
}
static __device__ __forceinline__ float bf2f(ushort u) {
    return __uint_as_float(((uint)u) << 16);
}

// lgkm-only barrier: LDS writes must be visible, but leave global loads in
// flight (no vmcnt drain).  sched_barrier stops motion across it (rule #18).
static __device__ __forceinline__ void wg_barrier() {
    asm volatile("s_waitcnt lgkmcnt(0)" ::: "memory");
    __builtin_amdgcn_s_barrier();
    __builtin_amdgcn_sched_barrier(0);
}

// fmax over the 2x4 epilogue tile in a FIXED order so the tracking path and
// the rn-only path produce bitwise-equal maxima.
static __device__ __forceinline__ float vmax24(const float v[2][4]) {
    float m = 0.0f;
    #pragma unroll
    for (int t = 0; t < 2; ++t)
        #pragma unroll
        for (int r = 0; r < 4; ++r) m = fmaxf(m, v[t][r]);
    return m;
}

// ---- prep: Et[j][i] = bf16(exp(trans[i][j])), Em[i][j] = bf16(exp(trans[i][j]))
__global__ void prep_mats(const float* __restrict__ trans,
                          ushort* __restrict__ Et, ushort* __restrict__ Em) {
    int i = blockIdx.x;    // 256 (row of trans)
    int j = threadIdx.x;   // 256
    float e = exp2f(trans[i * T + j] * LOG2E);
    uint u = __float_as_uint(e);
    ushort h = (ushort)((u + 0x7FFFu + ((u >> 16) & 1u)) >> 16);  // RTNE
    Em[i * T + j] = h;     // exp(trans) row-major   (backward A-operand)
    Et[j * T + i] = h;     // exp(trans) transposed  (forward  A-operand)
}

// ---- prep: emx = bf16(exp(em)), elementwise over B*S*T
__global__ void prep_emx(const float* __restrict__ em, ushort* __restrict__ emx) {
    size_t i4 = ((size_t)blockIdx.x * blockDim.x + threadIdx.x) * 4;
    f32x4 e = *reinterpret_cast<const f32x4*>(&em[i4]);
    uint2 w;
    w.x = pack_bf16x2(exp2f(e[0] * LOG2E), exp2f(e[1] * LOG2E));
    w.y = pack_bf16x2(exp2f(e[2] * LOG2E), exp2f(e[3] * LOG2E));
    *reinterpret_cast<uint2*>(&emx[i4]) = w;
}

// ---- scan body: 8 waves per WG (512 thr), wave w owns j in [32w, 32w+32).
// Per wave per step: 2 m-tiles x 8 k-tiles = 16 MFMA.  The k-tile ORDER is
// rotated by wave id (kt = (kk+w)&7), folded into the A/B load ADDRESSES so
// all register indices stay compile-time static (rule #20): de-synchronizes
// the 8 waves' otherwise-identical LDS address streams (cross-wave bank
// conflicts).  Accumulators split 4-way (8 chains of depth 2) to halve the
// serial MFMA dependency latency.
template<bool PRE, int DIR>
static __device__ __forceinline__ void scan_body(
    const float* __restrict__ em, const ushort* __restrict__ emx,
    const int* __restrict__ mask, const float* __restrict__ startt,
    const float* __restrict__ endt, const ushort* __restrict__ Amat,
    float* __restrict__ vecbuf, int* __restrict__ lsbuf,
    const int scan, const int bg,
    ushort (&Al)[2][16][LDP], float (&mx2)[16][8])
{
    constexpr int NSTEP = DIR ? NSB : NSF;
    constexpr int PGRP  = (NSTEP + 7) / 8;

    const int tid  = threadIdx.x;
    const int w    = tid >> 6;          // wave 0..7
    const int lane = tid & 63;
    const int q    = lane >> 4;         // quad 0..3
    const int l    = lane & 15;         // local batch 0..15
    const int b    = bg * 16 + l;

    // step idx -> em row (epilogue) / mask row (the where())
    #define EROW(ix) (DIR ? (S - 2 - (ix)) : (1 + (ix)))
    #define MROW(ix) (DIR ? (S - 1 - (ix)) : (1 + (ix)))

    // per-wave rotated k-tile byte offsets within an Al row (runtime-uniform)
    int koff[8];
    #pragma unroll
    for (int kk = 0; kk < 8; ++kk)
        koff[kk] = ((kk + w) & 7) * 32 + q * 8;   // element offset in row

    // ---- A fragments (step-invariant), loaded in ROTATED order: 64 VGPRs
    bf16x8 Afr[2][8];
    #pragma unroll
    for (int t = 0; t < 2; ++t) {
        int j = w * 32 + t * 16 + l;
        #pragma unroll
        for (int kk = 0; kk < 8; ++kk)
            Afr[t][kk] = *reinterpret_cast<const bf16x8*>(&Amat[j * T + koff[kk]]);
    }

    const float*  emrow = em  + (size_t)b * S * T;
    const ushort* exrow = PRE ? emx + (size_t)b * S * T : nullptr;
    const int*    mrow  = mask + (size_t)b * S;

    int ls = 0;
    int buf = 0;
    float areg[2][4];   // DIR=1: raw beta (pre-em), scaled. DIR=0: unused.

    // ---- init
    {
        const int    r0 = DIR ? (S - 1) : 0;
        const float* tv = DIR ? endt : startt;
        float v0[2][4], gg[2][4]; float mx = 0.0f;
        #pragma unroll
        for (int t = 0; t < 2; ++t) {
            int j0 = w * 32 + t * 16 + q * 4;
            f32x4 e4 = *reinterpret_cast<const f32x4*>(&emrow[(size_t)r0 * T + j0]);
            f32x4 s4 = *reinterpret_cast<const f32x4*>(&tv[j0]);
            #pragma unroll
            for (int r = 0; r < 4; ++r) {
                float full = exp2f((e4[r] + s4[r]) * LOG2E);
                v0[t][r] = full;
                gg[t][r] = DIR ? exp2f(s4[r] * LOG2E) : full;
                mx = fmaxf(mx, full);
            }
        }
        mx = fmaxf(mx, __shfl_xor(mx, 16));
        mx = fmaxf(mx, __shfl_xor(mx, 32));
        if (q == 0) mx2[l][w] = mx;
        __syncthreads();
        f32x4 ma = *reinterpret_cast<const f32x4*>(&mx2[l][0]);
        f32x4 mb = *reinterpret_cast<const f32x4*>(&mx2[l][4]);
        float gmx = fmaxf(fmaxf(fmaxf(ma[0], ma[1]), fmaxf(ma[2], ma[3])),
                          fmaxf(fmaxf(mb[0], mb[1]), fmaxf(mb[2], mb[3])));
        int e = (int)((__float_as_uint(gmx) >> 23) & 255u) - 127;
        float sc = __uint_as_float((uint)(127 - e) << 23);   // exact 2^-e
        ls = e;
        #pragma unroll
        for (int t = 0; t < 2; ++t) {
            int j0 = w * 32 + t * 16 + q * 4;
            uint2 wv;
            wv.x = pack_bf16x2(v0[t][0] * sc, v0[t][1] * sc);
            wv.y = pack_bf16x2(v0[t][2] * sc, v0[t][3] * sc);
            *reinterpret_cast<uint2*>(&Al[0][l][j0]) = wv;
            if (DIR) {
                #pragma unroll
                for (int r = 0; r < 4; ++r) areg[t][r] = gg[t][r] * sc;
            }
        }
        __syncthreads();
        if (q == 0) mx2[l][w] = mx * sc;
        __syncthreads();
    }

    // full per-step max tracking only needed when the stored vector can
    // persist across a masked step: forward score chain only.
    const bool track = (DIR == 0) && (scan != 0);

    // ---- preload em/mask for group 0 (idx 0..7)
    uint2 exv[8][2]; int mks[8];
    #pragma unroll
    for (int u = 0; u < 8; ++u) {
        int iu = u < NSTEP ? u : NSTEP - 1;
        #pragma unroll
        for (int t = 0; t < 2; ++t) {
            int j0 = w * 32 + t * 16 + q * 4;
            if (PRE) exv[u][t] = *reinterpret_cast<const uint2*>(&exrow[(size_t)EROW(iu) * T + j0]);
        }
        mks[u] = (scan && u < NSTEP) ? mrow[MROW(iu)] : 1;
    }

    for (int p = 0; p < PGRP; ++p) {
        // ---- issue next group's loads now (stay in flight across barriers)
        uint2 exn[8][2]; int mkn[8];
        #pragma unroll
        for (int u = 0; u < 8; ++u) {
            int idx  = 8 * (p + 1) + u;
            int idxc = idx < NSTEP ? idx : NSTEP - 1;
            #pragma unroll
            for (int t = 0; t < 2; ++t) {
                int j0 = w * 32 + t * 16 + q * 4;
                if (PRE) exn[u][t] = *reinterpret_cast<const uint2*>(&exrow[(size_t)EROW(idxc) * T + j0]);
            }
            mkn[u] = (scan && idx < NSTEP) ? mrow[MROW(idxc)] : 1;
        }

        float pend = 1.0f, vml = 0.0f; int pk = 0;

        #pragma unroll
        for (int u = 0; u < 8; ++u) {
            const int idx = 8 * p + u;
            if (idx < NSTEP) {
                if ((u & 3) == 0) {   // renorm-group start: derive kappa
                    f32x4 ma = *reinterpret_cast<const f32x4*>(&mx2[l][0]);
                    f32x4 mb = *reinterpret_cast<const f32x4*>(&mx2[l][4]);
                    float gmx = fmaxf(fmaxf(fmaxf(ma[0], ma[1]), fmaxf(ma[2], ma[3])),
                                      fmaxf(fmaxf(mb[0], mb[1]), fmaxf(mb[2], mb[3])));
                    int kap = (int)((__float_as_uint(gmx) >> 23) & 255u) - 127;
                    pend = __uint_as_float((uint)(127 - kap) << 23);
                    pk   = kap;
                    vml  = gmx;
                }
                const int nb = buf ^ 1;

                // B fragments (rotated order), then the MFMA block
                bf16x8 bfr[8];
                #pragma unroll
                for (int kk = 0; kk < 8; ++kk)
                    bfr[kk] = *reinterpret_cast<const bf16x8*>(&Al[buf][l][koff[kk]]);

                // 8 independent chains (2 m-tiles x 4 kk-classes), depth 2
                f32x4 ac[2][4] = {{f32x4{0,0,0,0}, f32x4{0,0,0,0}, f32x4{0,0,0,0}, f32x4{0,0,0,0}},
                                  {f32x4{0,0,0,0}, f32x4{0,0,0,0}, f32x4{0,0,0,0}, f32x4{0,0,0,0}}};
                #pragma unroll
                for (int kk = 0; kk < 8; ++kk) {
                    #pragma unroll
                    for (int t = 0; t < 2; ++t)
                        ac[t][kk & 3] = __builtin_amdgcn_mfma_f32_16x16x32_bf16(Afr[t][kk], bfr[kk], ac[t][kk & 3], 0, 0, 0);
                }
                f32x4 acc[2];
                #pragma unroll
                for (int t = 0; t < 2; ++t)
                    acc[t] = (ac[t][0] + ac[t][1]) + (ac[t][2] + ac[t][3]);

                const int mk = mks[u];
                float v[2][4];

                #pragma unroll
                for (int t = 0; t < 2; ++t) {
                    float e_[4];
                    if (PRE) {
                        e_[0] = bf2f((ushort)(exv[u][t].x & 0xFFFF));
                        e_[1] = bf2f((ushort)(exv[u][t].x >> 16));
                        e_[2] = bf2f((ushort)(exv[u][t].y & 0xFFFF));
                        e_[3] = bf2f((ushort)(exv[u][t].y >> 16));
                    } else {
                        int j0 = w * 32 + t * 16 + q * 4;
                        f32x4 e4 = *reinterpret_cast<const f32x4*>(&emrow[(size_t)EROW(idx) * T + j0]);
                        #pragma unroll
                        for (int r = 0; r < 4; ++r) e_[r] = exp2f(e4[r] * LOG2E);
                    }
                    if (DIR == 0) {
                        #pragma unroll
                        for (int r = 0; r < 4; ++r)
                            v[t][r] = acc[t][r] * e_[r] * pend;
                    } else {
                        #pragma unroll
                        for (int r = 0; r < 4; ++r) {
                            float g  = acc[t][r] * pend;
                            float sv = mk ? g : areg[t][r];
                            areg[t][r] = sv;
                            v[t][r] = sv * e_[r];
                        }
                    }
                }

                // LDS write of the new stored vector
                if (DIR == 0) {
                    if (mk) {
                        #pragma unroll
                        for (int t = 0; t < 2; ++t) {
                            int j0 = w * 32 + t * 16 + q * 4;
                            uint2 wv;
                            wv.x = pack_bf16x2(v[t][0], v[t][1]);
                            wv.y = pack_bf16x2(v[t][2], v[t][3]);
                            *reinterpret_cast<uint2*>(&Al[nb][l][j0]) = wv;
                        }
                    } else {
                        #pragma unroll
                        for (int t = 0; t < 2; ++t) {
                            int j0 = w * 32 + t * 16 + q * 4;
                            *reinterpret_cast<uint2*>(&Al[nb][l][j0]) =
                                *reinterpret_cast<const uint2*>(&Al[buf][l][j0]);
                        }
                    }
                } else {
                    #pragma unroll
                    for (int t = 0; t < 2; ++t) {
                        int j0 = w * 32 + t * 16 + q * 4;
                        uint2 wv;
                        wv.x = pack_bf16x2(v[t][0], v[t][1]);
                        wv.y = pack_bf16x2(v[t][2], v[t][3]);
                        *reinterpret_cast<uint2*>(&Al[nb][l][j0]) = wv;
                    }
                }

                // per-step max tracking only where needed (fwd score chain)
                if (track) {
                    float lmx = vmax24(v);
                    vml = mk ? lmx : vml;
                }
                ls  += mk ? pk : 0;
                pend = mk ? 1.0f : pend;
                pk   = mk ? 0 : pk;

                const bool rn = ((u & 3) == 3) || (idx == NSTEP - 1);
                if (rn) {   // publish stored-vector max for next renorm group
                    float fm = track ? vml : vmax24(v);
                    fm = fmaxf(fm, __shfl_xor(fm, 16));
                    fm = fmaxf(fm, __shfl_xor(fm, 32));
                    if (q == 0) mx2[l][w] = fm;
                }

                wg_barrier();
                buf = nb;
            }
        }

        #pragma unroll
        for (int u = 0; u < 8; ++u) {
            #pragma unroll
            for (int t = 0; t < 2; ++t) exv[u][t] = exn[u][t];
            mks[u] = mkn[u];
        }
    }

    // ---- write mid vector + exponent to workspace
    const int cidx = scan * 2 + DIR;
    if (DIR) {
        // areg holds raw G_{H+1} (scaled), f32
        #pragma unroll
        for (int t = 0; t < 2; ++t) {
            int j0 = w * 32 + t * 16 + q * 4;
            f32x4 o = {areg[t][0], areg[t][1], areg[t][2], areg[t][3]};
            *reinterpret_cast<f32x4*>(&vecbuf[((size_t)cidx * B + b) * T + j0]) = o;
        }
    } else {
        // stored alpha_H (scaled), bf16 in LDS
        #pragma unroll
        for (int t = 0; t < 2; ++t) {
            int j0 = w * 32 + t * 16 + q * 4;
            uint2 wv = *reinterpret_cast<const uint2*>(&Al[buf][l][j0]);
            f32x4 o = {bf2f((ushort)(wv.x & 0xFFFF)), bf2f((ushort)(wv.x >> 16)),
                       bf2f((ushort)(wv.y & 0xFFFF)), bf2f((ushort)(wv.y >> 16))};
            *reinterpret_cast<f32x4*>(&vecbuf[((size_t)cidx * B + b) * T + j0]) = o;
        }
    }
    if (w == 0 && q == 0) lsbuf[cidx * B + b] = ls;

    #undef EROW
    #undef MROW
}

template<bool PRE>
__launch_bounds__(512, 1)
__global__ void crf_scan(const float* __restrict__ em,
                         const ushort* __restrict__ emx,
                         const int* __restrict__ mask,
                         const float* __restrict__ startt,
                         const float* __restrict__ endt,
                         const ushort* __restrict__ Et,     // fwd A
                         const ushort* __restrict__ Emat,   // bwd A
                         float* __restrict__ vecbuf,
                         int* __restrict__ lsbuf)
{
    __shared__ __align__(16) ushort Al[2][16][LDP];
    __shared__ __align__(16) float mx2[16][8];

    const int scan = blockIdx.x & 1;
    const int dir  = (blockIdx.x >> 1) & 1;
    const int bg   = blockIdx.x >> 2;

    if (dir == 0)
        scan_body<PRE, 0>(em, emx, mask, startt, endt, Et,   vecbuf, lsbuf, scan, bg, Al, mx2);
    else
        scan_body<PRE, 1>(em, emx, mask, startt, endt, Emat, vecbuf, lsbuf, scan, bg, Al, mx2);
}

// ---- combine: res[scan][b] = ls_f + ls_b + log2(dot(alpha_H, G_{H+1}));
//      out[b] = (partition - score) * ln2
__global__ void combine2(const float* __restrict__ vecbuf, const int* __restrict__ lsbuf,
                         float* __restrict__ out) {
    __shared__ float r2[2][B];
    int tid = threadIdx.x;          // 256
    int sc_ = tid >> 7, b = tid & 127;
    const float* vf = vecbuf + ((size_t)(sc_ * 2 + 0) * B + b) * T;
    const float* vb = vecbuf + ((size_t)(sc_ * 2 + 1) * B + b) * T;
    float dot = 0.0f;
    for (int j = 0; j < T; j += 4) {
        f32x4 a = *reinterpret_cast<const f32x4*>(&vf[j]);
        f32x4 c = *reinterpret_cast<const f32x4*>(&vb[j]);
        dot += a[0] * c[0] + a[1] * c[1] + a[2] * c[2] + a[3] * c[3];
    }
    r2[sc_][b] = (float)(lsbuf[(sc_ * 2) * B + b] + lsbuf[(sc_ * 2 + 1) * B + b]) + log2f(dot);
    __syncthreads();
    if (tid < B) out[tid] = (r2[0][tid] - r2[1][tid]) * LN2;
}

extern "C" void kernel_launch(void* const* d_in, const int* in_sizes, int n_in,
                              void* d_out, int out_size, void* d_ws, size_t ws_size,
                              hipStream_t stream) {
    (void)in_sizes; (void)n_in; (void)out_size;
    const float* em = (const float*)d_in[0];
    const int*   mk = (const int*)d_in[1];
    const float* st = (const float*)d_in[2];
    const float* en = (const float*)d_in[3];
    const float* tr = (const float*)d_in[4];

    const size_t emx_bytes = (size_t)B * S * T * sizeof(ushort);   // 32 MiB
    const size_t mat_bytes = (size_t)T * T * sizeof(ushort);       // 128 KiB
    const size_t vec_bytes = (size_t)4 * B * T * sizeof(float);    // 512 KiB
    const size_t ls_bytes  = (size_t)4 * B * sizeof(int);          // 2 KiB

    const bool pre = ws_size >= emx_bytes + 2 * mat_bytes + vec_bytes + ls_bytes;

    char* wp = (char*)d_ws;
    ushort* emx = nullptr;
    if (pre) { emx = (ushort*)wp; wp += emx_bytes; }
    ushort* Et = (ushort*)wp; wp += mat_bytes;
    ushort* Em = (ushort*)wp; wp += mat_bytes;
    float*  vec = (float*)wp; wp += vec_bytes;
    int*    lsb = (int*)wp;

    prep_mats<<<T, T, 0, stream>>>(tr, Et, Em);
    if (pre) {
        prep_emx<<<(B * S * T) / (256 * 4), 256, 0, stream>>>(em, emx);
        crf_scan<true><<<32, 512, 0, stream>>>(em, emx, mk, st, en, Et, Em, vec, lsb);
    } else {
        crf_scan<false><<<32, 512, 0, stream>>>(em, emx, mk, st, en, Et, Em, vec, lsb);
    }
    combine2<<<1, 256, 0, stream>>>(vec, lsb, (float*)d_out);
}

// Round 6
// 345.768 us; speedup vs baseline: 1.4019x; 1.2062x over previous
//
#include <hip/hip_runtime.h>
#include <hip/hip_bf16.h>
#include <stdint.h>

#define LOG2E 1.44269504088896340736f
#define LN2   0.69314718055994530942f

typedef __attribute__((ext_vector_type(8))) __bf16 bf16x8;
typedef __attribute__((ext_vector_type(4))) float  f32x4;

static constexpr int B = 128, S = 512, T = 256;
static constexpr int LDP = T + 8;   // padded LDS row (bf16 elems)
static constexpr int H   = 258;     // forward covers s=1..H, backward s=S-1..H+1
static constexpr int NSF = H;           // 258 forward steps
static constexpr int NSB = S - 1 - H;   // 253 backward steps

static __device__ __forceinline__ uint pack_bf16x2(float a, float b) {
    __hip_bfloat162 h = __float22bfloat162_rn(make_float2(a, b));
    union { __hip_bfloat162 h; uint u; } cv; cv.h = h;
    return cv.u;
}
static __device__ __forceinline__ float bf2f(ushort u) {
    return __uint_as_float(((uint)u) << 16);
}

// lgkm-only barrier: LDS writes must be visible, but leave global loads in
// flight (no vmcnt drain).  sched_barrier stops motion across it (rule #18).
static __device__ __forceinline__ void wg_barrier() {
    asm volatile("s_waitcnt lgkmcnt(0)" ::: "memory");
    __builtin_amdgcn_s_barrier();
    __builtin_amdgcn_sched_barrier(0);
}

// fmax over the 2x4 epilogue tile in a FIXED order so the tracking path and
// the rn-only path produce bitwise-equal maxima.
static __device__ __forceinline__ float vmax24(const float v[2][4]) {
    float m = 0.0f;
    #pragma unroll
    for (int t = 0; t < 2; ++t)
        #pragma unroll
        for (int r = 0; r < 4; ++r) m = fmaxf(m, v[t][r]);
    return m;
}

// ---- prep: Et[j][i] = bf16(exp(trans[i][j])), Em[i][j] = bf16(exp(trans[i][j]))
__global__ void prep_mats(const float* __restrict__ trans,
                          ushort* __restrict__ Et, ushort* __restrict__ Em) {
    int i = blockIdx.x;    // 256 (row of trans)
    int j = threadIdx.x;   // 256
    float e = exp2f(trans[i * T + j] * LOG2E);
    uint u = __float_as_uint(e);
    ushort h = (ushort)((u + 0x7FFFu + ((u >> 16) & 1u)) >> 16);  // RTNE
    Em[i * T + j] = h;     // exp(trans) row-major   (backward A-operand)
    Et[j * T + i] = h;     // exp(trans) transposed  (forward  A-operand)
}

// ---- scan body: 8 waves per WG (512 thr), wave w owns j in [32w, 32w+32).
// Exact R3 structure (best measured: 1.04 us/step): straight k-tile order,
// 2-way accumulator split, lgkm-only barrier.  em is read as f32 directly
// (no precomputed emx): loads prefetched one 4-step group ahead; exp2f is
// computed from prefetched registers BEFORE the MFMA block, so it rides in
// the VALU shadow of the other wave's MFMAs and stays off the critical path.
template<int DIR>
static __device__ __forceinline__ void scan_body(
    const float* __restrict__ em,
    const int* __restrict__ mask, const float* __restrict__ startt,
    const float* __restrict__ endt, const ushort* __restrict__ Amat,
    float* __restrict__ vecbuf, int* __restrict__ lsbuf,
    const int scan, const int bg,
    ushort (&Al)[2][16][LDP], float (&mx2)[16][8])
{
    constexpr int NSTEP = DIR ? NSB : NSF;
    constexpr int PGRP  = (NSTEP + 3) / 4;

    const int tid  = threadIdx.x;
    const int w    = tid >> 6;          // wave 0..7
    const int lane = tid & 63;
    const int q    = lane >> 4;         // quad 0..3
    const int l    = lane & 15;         // local batch 0..15
    const int b    = bg * 16 + l;

    // step idx -> em row (epilogue) / mask row (the where())
    #define EROW(ix) (DIR ? (S - 2 - (ix)) : (1 + (ix)))
    #define MROW(ix) (DIR ? (S - 1 - (ix)) : (1 + (ix)))

    // ---- A fragments (step-invariant): 64 VGPRs/wave
    bf16x8 Afr[2][8];
    #pragma unroll
    for (int t = 0; t < 2; ++t) {
        int j = w * 32 + t * 16 + l;
        #pragma unroll
        for (int kt = 0; kt < 8; ++kt)
            Afr[t][kt] = *reinterpret_cast<const bf16x8*>(&Amat[j * T + kt * 32 + q * 8]);
    }

    const float* emrow = em  + (size_t)b * S * T;
    const int*   mrow  = mask + (size_t)b * S;

    int ls = 0;
    int buf = 0;
    float areg[2][4];   // DIR=1: raw beta (pre-em), scaled. DIR=0: unused.

    // ---- init
    {
        const int    r0 = DIR ? (S - 1) : 0;
        const float* tv = DIR ? endt : startt;
        float v0[2][4], gg[2][4]; float mx = 0.0f;
        #pragma unroll
        for (int t = 0; t < 2; ++t) {
            int j0 = w * 32 + t * 16 + q * 4;
            f32x4 e4 = *reinterpret_cast<const f32x4*>(&emrow[(size_t)r0 * T + j0]);
            f32x4 s4 = *reinterpret_cast<const f32x4*>(&tv[j0]);
            #pragma unroll
            for (int r = 0; r < 4; ++r) {
                float full = exp2f((e4[r] + s4[r]) * LOG2E);
                v0[t][r] = full;
                gg[t][r] = DIR ? exp2f(s4[r] * LOG2E) : full;
                mx = fmaxf(mx, full);
            }
        }
        mx = fmaxf(mx, __shfl_xor(mx, 16));
        mx = fmaxf(mx, __shfl_xor(mx, 32));
        if (q == 0) mx2[l][w] = mx;
        __syncthreads();
        f32x4 ma = *reinterpret_cast<const f32x4*>(&mx2[l][0]);
        f32x4 mb = *reinterpret_cast<const f32x4*>(&mx2[l][4]);
        float gmx = fmaxf(fmaxf(fmaxf(ma[0], ma[1]), fmaxf(ma[2], ma[3])),
                          fmaxf(fmaxf(mb[0], mb[1]), fmaxf(mb[2], mb[3])));
        int e = (int)((__float_as_uint(gmx) >> 23) & 255u) - 127;
        float sc = __uint_as_float((uint)(127 - e) << 23);   // exact 2^-e
        ls = e;
        #pragma unroll
        for (int t = 0; t < 2; ++t) {
            int j0 = w * 32 + t * 16 + q * 4;
            uint2 wv;
            wv.x = pack_bf16x2(v0[t][0] * sc, v0[t][1] * sc);
            wv.y = pack_bf16x2(v0[t][2] * sc, v0[t][3] * sc);
            *reinterpret_cast<uint2*>(&Al[0][l][j0]) = wv;
            if (DIR) {
                #pragma unroll
                for (int r = 0; r < 4; ++r) areg[t][r] = gg[t][r] * sc;
            }
        }
        __syncthreads();
        if (q == 0) mx2[l][w] = mx * sc;
        __syncthreads();
    }

    // full per-step max tracking only needed when the stored vector can
    // persist across a masked step: forward score chain only.
    const bool track = (DIR == 0) && (scan != 0);

    // ---- preload em/mask for group 0 (idx 0..3), f32
    f32x4 exv[4][2]; int mks[4];
    #pragma unroll
    for (int u = 0; u < 4; ++u) {
        int iu = u < NSTEP ? u : NSTEP - 1;
        #pragma unroll
        for (int t = 0; t < 2; ++t) {
            int j0 = w * 32 + t * 16 + q * 4;
            exv[u][t] = *reinterpret_cast<const f32x4*>(&emrow[(size_t)EROW(iu) * T + j0]);
        }
        mks[u] = (scan && u < NSTEP) ? mrow[MROW(iu)] : 1;
    }

    for (int p = 0; p < PGRP; ++p) {
        // ---- issue next group's loads now (stay in flight across barriers)
        f32x4 exn[4][2]; int mkn[4];
        #pragma unroll
        for (int u = 0; u < 4; ++u) {
            int idx  = 4 * (p + 1) + u;
            int idxc = idx < NSTEP ? idx : NSTEP - 1;
            #pragma unroll
            for (int t = 0; t < 2; ++t) {
                int j0 = w * 32 + t * 16 + q * 4;
                exn[u][t] = *reinterpret_cast<const f32x4*>(&emrow[(size_t)EROW(idxc) * T + j0]);
            }
            mkn[u] = (scan && idx < NSTEP) ? mrow[MROW(idxc)] : 1;
        }

        float pend = 1.0f, vml = 0.0f; int pk = 0;

        #pragma unroll
        for (int u = 0; u < 4; ++u) {
            const int idx = 4 * p + u;
            if (idx < NSTEP) {
                if (u == 0) {   // renorm-group start: derive kappa
                    f32x4 ma = *reinterpret_cast<const f32x4*>(&mx2[l][0]);
                    f32x4 mb = *reinterpret_cast<const f32x4*>(&mx2[l][4]);
                    float gmx = fmaxf(fmaxf(fmaxf(ma[0], ma[1]), fmaxf(ma[2], ma[3])),
                                      fmaxf(fmaxf(mb[0], mb[1]), fmaxf(mb[2], mb[3])));
                    int kap = (int)((__float_as_uint(gmx) >> 23) & 255u) - 127;
                    pend = __uint_as_float((uint)(127 - kap) << 23);
                    pk   = kap;
                    vml  = gmx;
                }
                const int nb = buf ^ 1;

                // exp(em) for this step, from registers loaded a group ago:
                // independent of acc/bfr -> scheduled under MFMA shadow.
                float ex_[2][4];
                #pragma unroll
                for (int t = 0; t < 2; ++t)
                    #pragma unroll
                    for (int r = 0; r < 4; ++r)
                        ex_[t][r] = exp2f(exv[u][t][r] * LOG2E);

                // B fragments, then the MFMA block
                bf16x8 bfr[8];
                #pragma unroll
                for (int kt = 0; kt < 8; ++kt)
                    bfr[kt] = *reinterpret_cast<const bf16x8*>(&Al[buf][l][kt * 32 + q * 8]);

                // 4 independent chains (2 m-tiles x even/odd kt), depth 4
                f32x4 ac[2][2] = {{f32x4{0,0,0,0}, f32x4{0,0,0,0}},
                                  {f32x4{0,0,0,0}, f32x4{0,0,0,0}}};
                #pragma unroll
                for (int kt = 0; kt < 8; ++kt) {
                    #pragma unroll
                    for (int t = 0; t < 2; ++t)
                        ac[t][kt & 1] = __builtin_amdgcn_mfma_f32_16x16x32_bf16(Afr[t][kt], bfr[kt], ac[t][kt & 1], 0, 0, 0);
                }
                f32x4 acc[2];
                #pragma unroll
                for (int t = 0; t < 2; ++t) acc[t] = ac[t][0] + ac[t][1];

                const int mk = mks[u];
                float v[2][4];

                #pragma unroll
                for (int t = 0; t < 2; ++t) {
                    if (DIR == 0) {
                        #pragma unroll
                        for (int r = 0; r < 4; ++r)
                            v[t][r] = acc[t][r] * ex_[t][r] * pend;
                    } else {
                        #pragma unroll
                        for (int r = 0; r < 4; ++r) {
                            float g  = acc[t][r] * pend;
                            float sv = mk ? g : areg[t][r];
                            areg[t][r] = sv;
                            v[t][r] = sv * ex_[t][r];
                        }
                    }
                }

                // LDS write of the new stored vector
                if (DIR == 0) {
                    if (mk) {
                        #pragma unroll
                        for (int t = 0; t < 2; ++t) {
                            int j0 = w * 32 + t * 16 + q * 4;
                            uint2 wv;
                            wv.x = pack_bf16x2(v[t][0], v[t][1]);
                            wv.y = pack_bf16x2(v[t][2], v[t][3]);
                            *reinterpret_cast<uint2*>(&Al[nb][l][j0]) = wv;
                        }
                    } else {
                        #pragma unroll
                        for (int t = 0; t < 2; ++t) {
                            int j0 = w * 32 + t * 16 + q * 4;
                            *reinterpret_cast<uint2*>(&Al[nb][l][j0]) =
                                *reinterpret_cast<const uint2*>(&Al[buf][l][j0]);
                        }
                    }
                } else {
                    #pragma unroll
                    for (int t = 0; t < 2; ++t) {
                        int j0 = w * 32 + t * 16 + q * 4;
                        uint2 wv;
                        wv.x = pack_bf16x2(v[t][0], v[t][1]);
                        wv.y = pack_bf16x2(v[t][2], v[t][3]);
                        *reinterpret_cast<uint2*>(&Al[nb][l][j0]) = wv;
                    }
                }

                // per-step max tracking only where needed (fwd score chain)
                if (track) {
                    float lmx = vmax24(v);
                    vml = mk ? lmx : vml;
                }
                ls  += mk ? pk : 0;
                pend = mk ? 1.0f : pend;
                pk   = mk ? 0 : pk;

                const bool rn = (u == 3) || (idx == NSTEP - 1);
                if (rn) {   // publish stored-vector max for next renorm group
                    float fm = track ? vml : vmax24(v);
                    fm = fmaxf(fm, __shfl_xor(fm, 16));
                    fm = fmaxf(fm, __shfl_xor(fm, 32));
                    if (q == 0) mx2[l][w] = fm;
                }

                wg_barrier();
                buf = nb;
            }
        }

        #pragma unroll
        for (int u = 0; u < 4; ++u) {
            #pragma unroll
            for (int t = 0; t < 2; ++t) exv[u][t] = exn[u][t];
            mks[u] = mkn[u];
        }
    }

    // ---- write mid vector + exponent to workspace
    const int cidx = scan * 2 + DIR;
    if (DIR) {
        // areg holds raw G_{H+1} (scaled), f32
        #pragma unroll
        for (int t = 0; t < 2; ++t) {
            int j0 = w * 32 + t * 16 + q * 4;
            f32x4 o = {areg[t][0], areg[t][1], areg[t][2], areg[t][3]};
            *reinterpret_cast<f32x4*>(&vecbuf[((size_t)cidx * B + b) * T + j0]) = o;
        }
    } else {
        // stored alpha_H (scaled), bf16 in LDS
        #pragma unroll
        for (int t = 0; t < 2; ++t) {
            int j0 = w * 32 + t * 16 + q * 4;
            uint2 wv = *reinterpret_cast<const uint2*>(&Al[buf][l][j0]);
            f32x4 o = {bf2f((ushort)(wv.x & 0xFFFF)), bf2f((ushort)(wv.x >> 16)),
                       bf2f((ushort)(wv.y & 0xFFFF)), bf2f((ushort)(wv.y >> 16))};
            *reinterpret_cast<f32x4*>(&vecbuf[((size_t)cidx * B + b) * T + j0]) = o;
        }
    }
    if (w == 0 && q == 0) lsbuf[cidx * B + b] = ls;

    #undef EROW
    #undef MROW
}

__launch_bounds__(512, 2)
__global__ void crf_scan(const float* __restrict__ em,
                         const int* __restrict__ mask,
                         const float* __restrict__ startt,
                         const float* __restrict__ endt,
                         const ushort* __restrict__ Et,     // fwd A
                         const ushort* __restrict__ Emat,   // bwd A
                         float* __restrict__ vecbuf,
                         int* __restrict__ lsbuf)
{
    __shared__ __align__(16) ushort Al[2][16][LDP];
    __shared__ __align__(16) float mx2[16][8];

    const int scan = blockIdx.x & 1;
    const int dir  = (blockIdx.x >> 1) & 1;
    const int bg   = blockIdx.x >> 2;

    if (dir == 0)
        scan_body<0>(em, mask, startt, endt, Et,   vecbuf, lsbuf, scan, bg, Al, mx2);
    else
        scan_body<1>(em, mask, startt, endt, Emat, vecbuf, lsbuf, scan, bg, Al, mx2);
}

// ---- combine: one block per batch b; 256 threads reduce both scans' dots.
// res[scan][b] = ls_f + ls_b + log2(dot(alpha_H, G_{H+1}));
// out[b] = (partition - score) * ln2
__global__ void combine2(const float* __restrict__ vecbuf, const int* __restrict__ lsbuf,
                         float* __restrict__ out) {
    const int b = blockIdx.x;       // 128
    const int j = threadIdx.x;      // 256
    const float* vf0 = vecbuf + ((size_t)0 * B + b) * T;
    const float* vb0 = vecbuf + ((size_t)1 * B + b) * T;
    const float* vf1 = vecbuf + ((size_t)2 * B + b) * T;
    const float* vb1 = vecbuf + ((size_t)3 * B + b) * T;
    float p0 = vf0[j] * vb0[j];
    float p1 = vf1[j] * vb1[j];
    // wave reduce (identical op order for both scans)
    #pragma unroll
    for (int off = 32; off >= 1; off >>= 1) {
        p0 += __shfl_xor(p0, off);
        p1 += __shfl_xor(p1, off);
    }
    __shared__ float s0[4], s1[4];
    const int wv = j >> 6, ln = j & 63;
    if (ln == 0) { s0[wv] = p0; s1[wv] = p1; }
    __syncthreads();
    if (j == 0) {
        float d0 = (s0[0] + s0[1]) + (s0[2] + s0[3]);
        float d1 = (s1[0] + s1[1]) + (s1[2] + s1[3]);
        float r0 = (float)(lsbuf[0 * B + b] + lsbuf[1 * B + b]) + log2f(d0);
        float r1 = (float)(lsbuf[2 * B + b] + lsbuf[3 * B + b]) + log2f(d1);
        out[b] = (r0 - r1) * LN2;
    }
}

extern "C" void kernel_launch(void* const* d_in, const int* in_sizes, int n_in,
                              void* d_out, int out_size, void* d_ws, size_t ws_size,
                              hipStream_t stream) {
    (void)in_sizes; (void)n_in; (void)out_size; (void)ws_size;
    const float* em = (const float*)d_in[0];
    const int*   mk = (const int*)d_in[1];
    const float* st = (const float*)d_in[2];
    const float* en = (const float*)d_in[3];
    const float* tr = (const float*)d_in[4];

    const size_t mat_bytes = (size_t)T * T * sizeof(ushort);       // 128 KiB
    const size_t vec_bytes = (size_t)4 * B * T * sizeof(float);    // 512 KiB

    char* wp = (char*)d_ws;
    ushort* Et = (ushort*)wp; wp += mat_bytes;
    ushort* Em = (ushort*)wp; wp += mat_bytes;
    float*  vec = (float*)wp; wp += vec_bytes;
    int*    lsb = (int*)wp;

    prep_mats<<<T, T, 0, stream>>>(tr, Et, Em);
    crf_scan<<<32, 512, 0, stream>>>(em, mk, st, en, Et, Em, vec, lsb);
    combine2<<<B, 256, 0, stream>>>(vec, lsb, (float*)d_out);
}